// Round 13
// baseline (243.320 us; speedup 1.0000x reference)
//
#include <hip/hip_runtime.h>
#include <hip/hip_fp16.h>

// B=64, I=2048, D=8, O=32, K=16.  e-layout o-major: e = o*16 + k.
//
// Round-13: delete the fold/redh machinery (issue-bound diagnosis: measured
// ~3000 VALU instr/thread vs ~1500 algorithmic; 8 barriers + vmcnt drains +
// redh round-trip per pass). New pass: wave owns 2 b's, loops the chunk's
// 8 i's, accumulates part in REGISTERS (acc[j] += c*uh[j]); W fragments
// re-read per i from packed W16 (8 coalesced float4/wave, L2-hot). 1 barrier
// total, LDS 2 KB, no redh. Store: 2 H8/lane -> full 128-B lines in the
// r12 part layout [64][8 q][256 ch][64 r]. prep + reduce: r12 verbatim.
//
// grid 1024 = (qh = bx>>8: b-quarter, 16 b's) x (ch = bx&255: 8-i chunk).
// wave w -> b-pair {qh*16+2w, +1}; lane: o = l&31, kk = l>>5.

typedef _Float16 hf2 __attribute__((ext_vector_type(2)));

struct __align__(16) H8 { __half2 a, b, c, d; };
struct __align__(8)  H4 { __half2 a, b; };

__device__ __forceinline__ float dot2(hf2 a, hf2 b, float c) {
#if __has_builtin(__builtin_amdgcn_fdot2)
    return __builtin_amdgcn_fdot2(a, b, c, false);   // v_dot2_f32_f16
#else
    return fmaf((float)a.x, (float)b.x, fmaf((float)a.y, (float)b.y, c));
#endif
}
__device__ __forceinline__ hf2 bch(float f) { return __builtin_bit_cast(hf2, f); }

template<int CTRL>
__device__ __forceinline__ float dppadd(float v) {   // v + dpp_perm(v), VALU-only
    return v + __int_as_float(__builtin_amdgcn_update_dpp(
        0, __float_as_int(v), CTRL, 0xF, 0xF, true));
}

// softmax weight c for one (b,i): uh . v, k-half combine, exp, o-sum, divide
__device__ __forceinline__ float softmax_c(const float uh[8], const H8& vv) {
    float2 v0 = __half22float2(vv.a), v1 = __half22float2(vv.b);
    float2 v2 = __half22float2(vv.c), v3 = __half22float2(vv.d);
    float logit = uh[0] * v0.x;
    logit = fmaf(uh[1], v0.y, logit);
    logit = fmaf(uh[2], v1.x, logit);
    logit = fmaf(uh[3], v1.y, logit);
    logit = fmaf(uh[4], v2.x, logit);
    logit = fmaf(uh[5], v2.y, logit);
    logit = fmaf(uh[6], v3.x, logit);
    logit = fmaf(uh[7], v3.y, logit);
    logit += __shfl_xor(logit, 32, 64);      // combine k-halves (1 DS)
    float ex = __expf(logit);                // |logit| small: no max
    float sm = ex;                           // o-sum: 4 DPP + xor16 swizzle
    sm = dppadd<0xB1>(sm);                   // quad_perm xor1
    sm = dppadd<0x4E>(sm);                   // quad_perm xor2
    sm = dppadd<0x124>(sm);                  // row_ror:4
    sm = dppadd<0x128>(sm);                  // row_ror:8
    sm += __int_as_float(__builtin_amdgcn_ds_swizzle(
              __float_as_int(sm), 0x401F));  // xor16 within 32
    return __fdividef(ex, sm);
}

// ---------------------------------------------------------------------------
// prep: W[2048][32][8][16] f32 -> W16[i][j 8][l 64][d2 4] packed hf2 (16 MB).
// ---------------------------------------------------------------------------
__global__ __launch_bounds__(512)
void prep_kernel(const float* __restrict__ W, float* __restrict__ W16)
{
    const int ch = blockIdx.x;               // 256 blocks: 8 i's each
    const int t  = threadIdx.x;
    const int is = t >> 6, l = t & 63, o = l & 31, kk = l >> 5;
    const int i  = ch * 8 + is;

    const float* wp = W + (size_t)(i * 32 + o) * 128 + kk * 8;
    float r[8][8];
    #pragma unroll
    for (int d = 0; d < 8; ++d) {
        float4 a = *(const float4*)(wp + d * 16);
        float4 b = *(const float4*)(wp + d * 16 + 4);
        r[d][0] = a.x; r[d][1] = a.y; r[d][2] = a.z; r[d][3] = a.w;
        r[d][4] = b.x; r[d][5] = b.y; r[d][6] = b.z; r[d][7] = b.w;
    }
    float4* dst = (float4*)W16 + (size_t)i * 512 + l;
    #pragma unroll
    for (int j = 0; j < 8; ++j) {
        float o4[4];
        #pragma unroll
        for (int d2 = 0; d2 < 4; ++d2) {
            hf2 p; p.x = (_Float16)r[2 * d2][j]; p.y = (_Float16)r[2 * d2 + 1][j];
            o4[d2] = __builtin_bit_cast(float, p);
        }
        dst[(size_t)j * 64] = make_float4(o4[0], o4[1], o4[2], o4[3]);
    }
}

template<int PASS0>
__global__ __launch_bounds__(512, 4)   // VGPR budget 128 (wf 32 + acc 16 + ...)
void pass_kernel(const float* __restrict__ x,     // [64][2048][8]
                 const float* __restrict__ W16,   // packed (see prep)
                 const __half* __restrict__ vin,  // [64][512] fp16, o-major
                 __half* __restrict__ part)       // [64][8][256][64] fp16
{
    __shared__ __align__(16) hf2 x_ldsh[16][8][4];   // 2 KB: [bl][i][d-pair]

    const int t  = threadIdx.x;
    const int w  = t >> 6;
    const int l  = t & 63;
    const int o  = l & 31;
    const int kk = l >> 5;
    const int bx = blockIdx.x;
    const int ch = bx & 255;
    const int qh = bx >> 8;          // b-quarter: b in [qh*16, qh*16+16)

    // ---- stage x packed fp16: 512 hf2, one per thread ----------------------
    {
        const int bl = t >> 5, wv = (t >> 2) & 7, d2 = t & 3;
        const float2 xx = *(const float2*)(
            x + (size_t)(qh * 16 + bl) * 16384 + (size_t)(ch * 8 + wv) * 8 + 2 * d2);
        hf2 p; p.x = (_Float16)xx.x; p.y = (_Float16)xx.y;
        x_ldsh[bl][wv][d2] = p;
    }

    const int b0 = qh * 16 + w * 2;  // this wave's two b's
    H8 vv0, vv1;
    if (!PASS0) {                    // issue early; L1/L2 (1 KB/wave, shared)
        vv0 = *(const H8*)(vin + (size_t)b0 * 512 + o * 16 + kk * 8);
        vv1 = *(const H8*)(vin + (size_t)(b0 + 1) * 512 + o * 16 + kk * 8);
    }
    __syncthreads();                 // x_ldsh ready (the only barrier)

    float acc0[8], acc1[8];
    #pragma unroll
    for (int j = 0; j < 8; ++j) { acc0[j] = 0.f; acc1[j] = 0.f; }

    const float4* wbase = (const float4*)W16 + (size_t)(ch * 8) * 512 + l;

    for (int i = 0; i < 8; ++i) {    // chunk's 8 input capsules
        float4 wf[8];                // this i's W fragment: 8 coalesced 16B
        #pragma unroll
        for (int j = 0; j < 8; ++j)
            wf[j] = wbase[(size_t)i * 512 + (size_t)j * 64];

        const hf2* xp0 = &x_ldsh[w * 2][i][0];       // wave-uniform broadcast
        const hf2* xp1 = &x_ldsh[w * 2 + 1][i][0];
        hf2 x00 = xp0[0], x01 = xp0[1], x02 = xp0[2], x03 = xp0[3];
        hf2 x10 = xp1[0], x11 = xp1[1], x12 = xp1[2], x13 = xp1[3];

        float uh0[8], uh1[8];
        #pragma unroll
        for (int j = 0; j < 8; ++j) {
            uh0[j] = dot2(x03, bch(wf[j].w), dot2(x02, bch(wf[j].z),
                     dot2(x01, bch(wf[j].y), dot2(x00, bch(wf[j].x), 0.f))));
            uh1[j] = dot2(x13, bch(wf[j].w), dot2(x12, bch(wf[j].z),
                     dot2(x11, bch(wf[j].y), dot2(x10, bch(wf[j].x), 0.f))));
        }
        if (PASS0) {                 // c uniform: factor out, scale at store
            #pragma unroll
            for (int j = 0; j < 8; ++j) { acc0[j] += uh0[j]; acc1[j] += uh1[j]; }
        } else {
            const float c0 = softmax_c(uh0, vv0);
            const float c1 = softmax_c(uh1, vv1);
            #pragma unroll
            for (int j = 0; j < 8; ++j) {
                acc0[j] = fmaf(c0, uh0[j], acc0[j]);
                acc1[j] = fmaf(c1, uh1[j], acc1[j]);
            }
        }
    }

    // ---- store: lane (o,kk) -> part[b][o>>2][ch][(o&3)*16 + kk*8], 16 B ----
    if (PASS0) {
        #pragma unroll
        for (int j = 0; j < 8; ++j) { acc0[j] *= 0.03125f; acc1[j] *= 0.03125f; }
    }
    const size_t roff = (size_t)(o >> 2) * 256 * 64 + (size_t)ch * 64
                      + (o & 3) * 16 + kk * 8;
    H8 pk;
    pk.a = __floats2half2_rn(acc0[0], acc0[1]);
    pk.b = __floats2half2_rn(acc0[2], acc0[3]);
    pk.c = __floats2half2_rn(acc0[4], acc0[5]);
    pk.d = __floats2half2_rn(acc0[6], acc0[7]);
    *(H8*)(part + (size_t)b0 * 8 * 256 * 64 + roff) = pk;
    pk.a = __floats2half2_rn(acc1[0], acc1[1]);
    pk.b = __floats2half2_rn(acc1[2], acc1[3]);
    pk.c = __floats2half2_rn(acc1[4], acc1[5]);
    pk.d = __floats2half2_rn(acc1[6], acc1[7]);
    *(H8*)(part + (size_t)(b0 + 1) * 8 * 256 * 64 + roff) = pk;
}

// ---------------------------------------------------------------------------
// Reduce (r12 verbatim): grid 512 = (b = bx>>3) x (q = bx&7). Slice part[b][q]
// = 32 KB contiguous. 3-stage LDS fold, squash tail.
// ---------------------------------------------------------------------------
template<int PHASE>
__global__ __launch_bounds__(1024)
void reduce_kernel(const __half* __restrict__ part,
                   __half* __restrict__ vsum,
                   float* __restrict__ out)
{
    __shared__ float sAf[256][68];                // 69.6 KB (padded)
    __shared__ float sB[16][64];                  //  4 KB
    const int bx = blockIdx.x;
    const int b  = bx >> 3;
    const int q  = bx & 7;
    const int t  = threadIdx.x;

    const __half* base = part + (((size_t)b * 8 + q) * 256) * 64;  // 16384 halves
    H8 v0 = *(const H8*)(base + t * 16);          // 2 x 16 B, contiguous
    H8 v1 = *(const H8*)(base + t * 16 + 8);
    const int ch = t >> 2, rq = t & 3;
    float* dst = &sAf[ch][rq * 16];
    {
        float2 f;
        f = __half22float2(v0.a); dst[0]  = f.x; dst[1]  = f.y;
        f = __half22float2(v0.b); dst[2]  = f.x; dst[3]  = f.y;
        f = __half22float2(v0.c); dst[4]  = f.x; dst[5]  = f.y;
        f = __half22float2(v0.d); dst[6]  = f.x; dst[7]  = f.y;
        f = __half22float2(v1.a); dst[8]  = f.x; dst[9]  = f.y;
        f = __half22float2(v1.b); dst[10] = f.x; dst[11] = f.y;
        f = __half22float2(v1.c); dst[12] = f.x; dst[13] = f.y;
        f = __half22float2(v1.d); dst[14] = f.x; dst[15] = f.y;
    }
    __syncthreads();

    {                                             // 256 ch -> 16 groups
        const int grp = t >> 6, r = t & 63;
        float sb = 0.f;
        #pragma unroll
        for (int cc = 0; cc < 16; ++cc)
            sb += sAf[grp * 16 + cc][r];
        sB[grp][r] = sb;
    }
    __syncthreads();

    if (t < 64) {                                 // one wave: 16 rows, squash
        float s1 = 0.f;
        #pragma unroll
        for (int grp = 0; grp < 16; ++grp) s1 += sB[grp][t];
        float sq = s1 * s1;
        #pragma unroll
        for (int off = 8; off >= 1; off >>= 1)
            sq += __shfl_xor(sq, off, 16);        // sum over 16 k within o
        float v = (sq / (1.f + sq) * rsqrtf(sq + 1e-7f)) * s1;
        const size_t idx = (size_t)b * 512 + q * 64 + t;
        if (PHASE == 2)      out[idx] = v;        // e = o*16+k == [b][o][k]
        else if (PHASE == 1) vsum[idx] = __float2half((float)vsum[idx] + v);
        else                 vsum[idx] = __float2half(v);
    }
}

// ---------------------------------------------------------------------------
extern "C" void kernel_launch(void* const* d_in, const int* in_sizes, int n_in,
                              void* d_out, int out_size, void* d_ws, size_t ws_size,
                              hipStream_t stream)
{
    const float* x = (const float*)d_in[0];
    const float* W = (const float*)d_in[1];
    float* out = (float*)d_out;
    char* ws = (char*)d_ws;

    const size_t partB = (size_t)64 * 8 * 256 * 64 * 2;     // 16 MB (fp16)
    const size_t vsumB = (size_t)64 * 512 * 2;              // 64 KB (fp16)
    const size_t w16B  = (size_t)2048 * 32 * 8 * 16 * 2;    // 16 MB (fp16)
    if (ws_size < partB + vsumB + w16B) return;             // <= proven 33.69 MB

    __half* part = (__half*)ws;
    __half* vsum = (__half*)(ws + partB);
    float*  W16  = (float*)(ws + partB + vsumB);

    // one-time W repack (must rerun every launch: ws may be re-poisoned)
    prep_kernel<<<256, 512, 0, stream>>>(W, W16);

    // round 0: c uniform -> v0; vsum = v0
    pass_kernel<1><<<1024, 512, 0, stream>>>(x, W16, vsum, part);
    reduce_kernel<0><<<512, 1024, 0, stream>>>(part, vsum, out);
    // round 1: logits = u_hat . v0 -> v1; vsum = v0 + v1
    pass_kernel<0><<<1024, 512, 0, stream>>>(x, W16, vsum, part);
    reduce_kernel<1><<<512, 1024, 0, stream>>>(part, vsum, out);
    // round 2: logits = u_hat . (v0+v1) -> v2 = output
    pass_kernel<0><<<1024, 512, 0, stream>>>(x, W16, vsum, part);
    reduce_kernel<2><<<512, 1024, 0, stream>>>(part, vsum, out);
}